// Round 6
// baseline (32948.157 us; speedup 1.0000x reference)
//
#include <hip/hip_runtime.h>

typedef __attribute__((ext_vector_type(8))) short sv8;   // 8 x bf16 (4 VGPRs)
typedef __attribute__((ext_vector_type(4))) float fv4;   // MFMA accumulator

#define NB 64
#define NT 512
#define NI 1024
#define NH 1024
#define NWG 256

__device__ __forceinline__ unsigned short f2bf(float f) {
  union { float f; unsigned u; } v; v.f = f;
  unsigned r = v.u + 0x7fffu + ((v.u >> 16) & 1u);  // round-to-nearest-even
  return (unsigned short)(r >> 16);
}

__device__ __forceinline__ float sigf(float x) {
  return 1.0f / (1.0f + __expf(-x));
}

// load 8 consecutive f32 and convert to a bf16x8 MFMA fragment (in-register)
__device__ __forceinline__ sv8 ldcvt8(const float* p) {
  float4 a = *reinterpret_cast<const float4*>(p);
  float4 b = *reinterpret_cast<const float4*>(p + 4);
  union { sv8 v; unsigned short u[8]; } r;
  r.u[0] = f2bf(a.x); r.u[1] = f2bf(a.y); r.u[2] = f2bf(a.z); r.u[3] = f2bf(a.w);
  r.u[4] = f2bf(b.x); r.u[5] = f2bf(b.y); r.u[6] = f2bf(b.z); r.u[7] = f2bf(b.w);
  return r.v;
}

// device-coherent (agent-scope, relaxed) accessors for the h double buffer.
__device__ __forceinline__ unsigned long long ld8_coh(const unsigned short* p) {
  return __hip_atomic_load((const unsigned long long*)p,
                           __ATOMIC_RELAXED, __HIP_MEMORY_SCOPE_AGENT);
}
__device__ __forceinline__ void st2_coh(unsigned short* p, unsigned short v) {
  __hip_atomic_store(p, v, __ATOMIC_RELAXED, __HIP_MEMORY_SCOPE_AGENT);
}

union hfrag { sv8 v; unsigned long long q[2]; };

__global__ void reset_cnt(unsigned* cnt) {
  if (threadIdx.x == 0)
    __hip_atomic_store(cnt, 0u, __ATOMIC_RELEASE, __HIP_MEMORY_SCOPE_AGENT);
}

// Hand-rolled grid barrier: monotone counter, agent-scope atomics.
// 256 WGs at 1 WG/CU on 256 CUs -> all co-resident (empirically: rounds 2-5
// completed in seconds, never hung -> barrier works).
__device__ __forceinline__ void grid_barrier(unsigned* cnt, unsigned k) {
  __threadfence();
  __syncthreads();
  if (threadIdx.x == 0) {
    __hip_atomic_fetch_add(cnt, 1u, __ATOMIC_ACQ_REL, __HIP_MEMORY_SCOPE_AGENT);
    const unsigned target = k * NWG;
    while (__hip_atomic_load(cnt, __ATOMIC_ACQUIRE, __HIP_MEMORY_SCOPE_AGENT) < target)
      __builtin_amdgcn_s_sleep(1);
    __threadfence();
  }
  __syncthreads();
}

// Persistent kernel, whole sequence. Grid 256 WGs x 256 thr, 1 WG/CU.
// WG w owns h-cols 4w..4w+3 -> preact cols n = g*NH + 4w + d, tile col c=g*4+d.
// Wave wv owns batch rows 16wv..16wv+15. Weight B-fragments in registers.
// x read f32 from d_in, converted in-register. OUTPUT IS FLOAT32.
__global__ void __launch_bounds__(256, 1) lstm_seq(
    const float* __restrict__ xf,            // [B][T][NI] f32 (d_in)
    const float* __restrict__ Wi,            // [4H][NI] f32
    const float* __restrict__ Wh,            // [4H][NH] f32
    float* out,                              // f32: hidden[B*T*H], h_T, c_T
    unsigned short* hbuf,                    // 2 * [NB][NH] bf16 double buffer
    unsigned* cnt)
{
  const int w    = blockIdx.x;
  const int tid  = threadIdx.x;
  const int lane = tid & 63;
  const int wv   = tid >> 6;
  const int c    = lane & 15;            // MFMA tile col
  const int ko   = (lane >> 4) << 3;     // k offset within a 32-k step
  const int n    = (c >> 2) * NH + (w << 2) + (c & 3);  // preact column

  __shared__ float pre[64][17];

  // ---- preload weight B-fragments (weight-stationary) ----
  sv8 bWi[32], bWh[32];
  {
    const float* wi = Wi + (size_t)n * NI + ko;
    const float* wh = Wh + (size_t)n * NH + ko;
#pragma unroll
    for (int kk = 0; kk < 32; ++kk) {
      union { sv8 v; unsigned short u[8]; } pi, ph;
#pragma unroll
      for (int j = 0; j < 8; ++j) {
        pi.u[j] = f2bf(wi[kk * 32 + j]);
        ph.u[j] = f2bf(wh[kk * 32 + j]);
      }
      bWi[kk] = pi.v;
      bWh[kk] = ph.v;
    }
  }

  // zero h_0 (buffer 0), coherent: 256 WGs x 256 thr == NB*NH exactly
  st2_coh(hbuf + (w << 8) + tid, 0);

  unsigned bar = 0;
  grid_barrier(cnt, ++bar);

  const int b    = tid >> 2;       // batch row in gate phase
  const int d    = tid & 3;
  const int jcol = (w << 2) + d;
  const int arow = (wv << 4) + c;  // batch row for A-fragments

  float cstate = 0.0f, hlast = 0.0f;

  for (int t = 0; t < NT; ++t) {
    const unsigned short* hr  = hbuf + (t & 1) * (NB * NH) + arow * NH + ko;
    const float*          xrf = xf + ((size_t)arow * NT + t) * NI + ko;

    // preact(64x16) = x_t @ Wi^T + h_t @ Wh^T ; 4 independent acc chains
    fv4 a0 = {0.f, 0.f, 0.f, 0.f}, a1 = a0, a2 = a0, a3 = a0;
#pragma unroll
    for (int kk = 0; kk < 32; kk += 2) {
      sv8 ax0 = ldcvt8(xrf + kk * 32);
      sv8 ax1 = ldcvt8(xrf + (kk + 1) * 32);
      hfrag h0, h1;
      h0.q[0] = ld8_coh(hr + kk * 32);
      h0.q[1] = ld8_coh(hr + kk * 32 + 4);
      h1.q[0] = ld8_coh(hr + (kk + 1) * 32);
      h1.q[1] = ld8_coh(hr + (kk + 1) * 32 + 4);
      a0 = __builtin_amdgcn_mfma_f32_16x16x32_bf16(ax0,  bWi[kk],     a0, 0, 0, 0);
      a1 = __builtin_amdgcn_mfma_f32_16x16x32_bf16(h0.v, bWh[kk],     a1, 0, 0, 0);
      a2 = __builtin_amdgcn_mfma_f32_16x16x32_bf16(ax1,  bWi[kk + 1], a2, 0, 0, 0);
      a3 = __builtin_amdgcn_mfma_f32_16x16x32_bf16(h1.v, bWh[kk + 1], a3, 0, 0, 0);
    }
    fv4 acc = (a0 + a2) + (a1 + a3);

    // D layout: row = (lane>>4)*4 + r, col = lane&15 (verified m89/m91)
    {
      int prow = (wv << 4) + ((lane >> 4) << 2);
#pragma unroll
      for (int r = 0; r < 4; ++r) pre[prow + r][c] = acc[r];
    }
    __syncthreads();

    // gates: thread (b,d) reads tile cols g*4+d
    float p0 = pre[b][d];        // i
    float p1 = pre[b][4 + d];    // f
    float p2 = pre[b][8 + d];    // o (reference quirk: o uses the 2H:3H chunk)
    float p3 = pre[b][12 + d];   // g
    float it = sigf(sigf(p0));
    float ft = sigf(sigf(p1));
    float ot = sigf(sigf(p2));
    float gt = tanhf(p3);
    cstate = ft * cstate + it * gt;
    float hv = ot * tanhf(cstate);
    hlast = hv;

    // recurrence store (bf16, device-coherent)
    st2_coh(hbuf + ((t & 1) ^ 1) * (NB * NH) + b * NH + jcol, f2bf(hv));
    // output store: FLOAT32
    out[(((size_t)b * NT + t) << 10) + jcol] = hv;

    grid_barrier(cnt, ++bar);  // h visible device-wide; protects pre & hbuf WAR
  }

  // h_T and c_T, FLOAT32
  out[(size_t)NB * NT * NH + b * NH + jcol]           = hlast;
  out[(size_t)NB * NT * NH + NB * NH + b * NH + jcol] = cstate;
}

extern "C" void kernel_launch(void* const* d_in, const int* in_sizes, int n_in,
                              void* d_out, int out_size, void* d_ws, size_t ws_size,
                              hipStream_t stream) {
  (void)in_sizes; (void)n_in; (void)out_size;
  const float* x  = (const float*)d_in[0];
  const float* Wi = (const float*)d_in[1];
  const float* Wh = (const float*)d_in[2];
  float* out = (float*)d_out;

  // ws usage (gated on ws_size):
  //   [0,64)           barrier counter (always; ws is guaranteed nonempty)
  //   [64, 64+256KiB)  hbuf bf16 double buffer, if it fits; else fall back to
  //                    the f32 h_T/c_T tail of d_out (524 KB; need 256 KB;
  //                    overwritten by the final f32 h_T/c_T stores).
  const size_t HBUF_OFF  = 64;
  const size_t HBUF_NEED = HBUF_OFF + (size_t)2 * NB * NH * 2;  // 262,208 B

  unsigned* cnt = (unsigned*)d_ws;
  unsigned short* hbuf = (ws_size >= HBUF_NEED)
      ? (unsigned short*)((char*)d_ws + HBUF_OFF)
      : (unsigned short*)(out + (size_t)NB * NT * NH);

  reset_cnt<<<dim3(1), dim3(64), 0, stream>>>(cnt);
  lstm_seq<<<dim3(NWG), dim3(256), 0, stream>>>(x, Wi, Wh, out, hbuf, cnt);
}

// Round 7
// 9822.787 us; speedup vs baseline: 3.3543x; 3.3543x over previous
//
#include <hip/hip_runtime.h>

typedef __attribute__((ext_vector_type(8))) short sv8;   // 8 x bf16 (4 VGPRs)
typedef __attribute__((ext_vector_type(4))) float fv4;   // MFMA accumulator

#define NB 64
#define NT 512
#define NI 1024
#define NH 1024
#define NWG 256

__device__ __forceinline__ unsigned short f2bf(float f) {
  union { float f; unsigned u; } v; v.f = f;
  unsigned r = v.u + 0x7fffu + ((v.u >> 16) & 1u);  // round-to-nearest-even
  return (unsigned short)(r >> 16);
}

__device__ __forceinline__ float sigf(float x) {
  return 1.0f / (1.0f + __expf(-x));
}

// load 8 consecutive f32 and convert to a bf16x8 MFMA fragment (in-register)
__device__ __forceinline__ sv8 ldcvt8(const float* p) {
  float4 a = *reinterpret_cast<const float4*>(p);
  float4 b = *reinterpret_cast<const float4*>(p + 4);
  union { sv8 v; unsigned short u[8]; } r;
  r.u[0] = f2bf(a.x); r.u[1] = f2bf(a.y); r.u[2] = f2bf(a.z); r.u[3] = f2bf(a.w);
  r.u[4] = f2bf(b.x); r.u[5] = f2bf(b.y); r.u[6] = f2bf(b.z); r.u[7] = f2bf(b.w);
  return r.v;
}

// MALL-coherent (agent-scope, RELAXED -> sc0 sc1, NO cache maintenance)
// accessors for the h double buffer. hbuf lines never live in L1/L2, so no
// buffer_inv/wbl2 is ever required for the recurrence.
__device__ __forceinline__ unsigned long long ld8_coh(const unsigned short* p) {
  return __hip_atomic_load((const unsigned long long*)p,
                           __ATOMIC_RELAXED, __HIP_MEMORY_SCOPE_AGENT);
}
__device__ __forceinline__ void st2_coh(unsigned short* p, unsigned short v) {
  __hip_atomic_store(p, v, __ATOMIC_RELAXED, __HIP_MEMORY_SCOPE_AGENT);
}

union hfrag { sv8 v; unsigned long long q[2]; };

__global__ void reset_cnt(unsigned* cnt) {
  if (threadIdx.x == 0)
    __hip_atomic_store(cnt, 0u, __ATOMIC_RELAXED, __HIP_MEMORY_SCOPE_AGENT);
}

// PATH A pre-pass: linear f32 -> bf16 of x into ws (only when ws is big enough).
__global__ void cvt_bf16_lin(const float* __restrict__ in,
                             unsigned short* __restrict__ out, int n4) {
  int i = blockIdx.x * blockDim.x + threadIdx.x;
  if (i >= n4) return;
  float4 v = reinterpret_cast<const float4*>(in)[i];
  ushort4 o;
  o.x = f2bf(v.x); o.y = f2bf(v.y); o.z = f2bf(v.z); o.w = f2bf(v.w);
  reinterpret_cast<ushort4*>(out)[i] = o;
}

// FENCE-FREE grid barrier. Correctness argument:
//  - __syncthreads() lowers to s_waitcnt vmcnt(0) lgkmcnt(0) + s_barrier, so
//    every wave's h-stores (sc0/sc1, write-through to MALL) are complete
//    before thread 0 arrives.
//  - cnt RMW/loads are agent-scope atomics executed at the coherence point.
//  - RELAXED everywhere: no buffer_inv / buffer_wbl2 (round 6 showed the
//    ACQUIRE-poll variant invalidates the XCD L2 every poll -> 64 us/step).
//  - Read-only data (x, Wi, Wh) can never be stale; out is write-only.
__device__ __forceinline__ void grid_barrier(unsigned* cnt, unsigned k) {
  __syncthreads();
  if (threadIdx.x == 0) {
    __hip_atomic_fetch_add(cnt, 1u, __ATOMIC_RELAXED, __HIP_MEMORY_SCOPE_AGENT);
    const unsigned target = k * NWG;
    while (__hip_atomic_load(cnt, __ATOMIC_RELAXED, __HIP_MEMORY_SCOPE_AGENT) < target)
      __builtin_amdgcn_s_sleep(4);
  }
  __syncthreads();
}

// Persistent kernel, whole sequence. Grid 256 WGs x 256 thr, 1 WG/CU.
// WG w owns h-cols 4w..4w+3 -> preact cols n = g*NH + 4w + d, tile col c=g*4+d.
// Wave wv owns batch rows 16wv..16wv+15. Weight B-fragments in registers.
// XBF=true : x read as bf16 from ws copy. XBF=false: f32 from d_in, cvt in-reg.
template <bool XBF>
__global__ void __launch_bounds__(256, 1) lstm_seq(
    const float* __restrict__ xf,            // [B][T][NI] f32 (d_in)
    const unsigned short* __restrict__ xb,   // [B][T][NI] bf16 (ws) or null
    const float* __restrict__ Wi,            // [4H][NI] f32
    const float* __restrict__ Wh,            // [4H][NH] f32
    float* out,                              // f32: hidden[B*T*H], h_T, c_T
    unsigned short* hbuf,                    // 2 * [NB][NH] bf16 double buffer
    unsigned* cnt)
{
  const int w    = blockIdx.x;
  const int tid  = threadIdx.x;
  const int lane = tid & 63;
  const int wv   = tid >> 6;
  const int c    = lane & 15;            // MFMA tile col
  const int ko   = (lane >> 4) << 3;     // k offset within a 32-k step
  const int n    = (c >> 2) * NH + (w << 2) + (c & 3);  // preact column

  __shared__ float pre[64][17];

  // ---- preload weight B-fragments (weight-stationary) ----
  sv8 bWi[32], bWh[32];
  {
    const float* wi = Wi + (size_t)n * NI + ko;
    const float* wh = Wh + (size_t)n * NH + ko;
#pragma unroll
    for (int kk = 0; kk < 32; ++kk) {
      union { sv8 v; unsigned short u[8]; } pi, ph;
#pragma unroll
      for (int j = 0; j < 8; ++j) {
        pi.u[j] = f2bf(wi[kk * 32 + j]);
        ph.u[j] = f2bf(wh[kk * 32 + j]);
      }
      bWi[kk] = pi.v;
      bWh[kk] = ph.v;
    }
  }

  // zero h_0 (buffer 0), coherent: 256 WGs x 256 thr == NB*NH exactly
  st2_coh(hbuf + (w << 8) + tid, 0);

  unsigned bar = 0;
  grid_barrier(cnt, ++bar);

  const int b    = tid >> 2;       // batch row in gate phase
  const int d    = tid & 3;
  const int jcol = (w << 2) + d;
  const int arow = (wv << 4) + c;  // batch row for A-fragments

  float cstate = 0.0f, hlast = 0.0f;

  for (int t = 0; t < NT; ++t) {
    const unsigned short* hr = hbuf + (t & 1) * (NB * NH) + arow * NH + ko;
    const unsigned short* xr =
        XBF ? (xb + ((size_t)arow * NT + t) * NI + ko) : nullptr;
    const float* xrf =
        XBF ? nullptr : (xf + ((size_t)arow * NT + t) * NI + ko);

    // preact(64x16) = x_t @ Wi^T + h_t @ Wh^T ; 4 independent acc chains
    fv4 a0 = {0.f, 0.f, 0.f, 0.f}, a1 = a0, a2 = a0, a3 = a0;
#pragma unroll
    for (int kk = 0; kk < 32; kk += 2) {
      sv8 ax0, ax1;
      if constexpr (XBF) {
        ax0 = *reinterpret_cast<const sv8*>(xr + kk * 32);
        ax1 = *reinterpret_cast<const sv8*>(xr + (kk + 1) * 32);
      } else {
        ax0 = ldcvt8(xrf + kk * 32);
        ax1 = ldcvt8(xrf + (kk + 1) * 32);
      }
      hfrag h0, h1;
      h0.q[0] = ld8_coh(hr + kk * 32);
      h0.q[1] = ld8_coh(hr + kk * 32 + 4);
      h1.q[0] = ld8_coh(hr + (kk + 1) * 32);
      h1.q[1] = ld8_coh(hr + (kk + 1) * 32 + 4);
      a0 = __builtin_amdgcn_mfma_f32_16x16x32_bf16(ax0,  bWi[kk],     a0, 0, 0, 0);
      a1 = __builtin_amdgcn_mfma_f32_16x16x32_bf16(h0.v, bWh[kk],     a1, 0, 0, 0);
      a2 = __builtin_amdgcn_mfma_f32_16x16x32_bf16(ax1,  bWi[kk + 1], a2, 0, 0, 0);
      a3 = __builtin_amdgcn_mfma_f32_16x16x32_bf16(h1.v, bWh[kk + 1], a3, 0, 0, 0);
    }
    fv4 acc = (a0 + a2) + (a1 + a3);

    // D layout: row = (lane>>4)*4 + r, col = lane&15 (verified m89/m91)
    {
      int prow = (wv << 4) + ((lane >> 4) << 2);
#pragma unroll
      for (int r = 0; r < 4; ++r) pre[prow + r][c] = acc[r];
    }
    __syncthreads();

    // gates: thread (b,d) reads tile cols g*4+d
    float p0 = pre[b][d];        // i
    float p1 = pre[b][4 + d];    // f
    float p2 = pre[b][8 + d];    // o (reference quirk: o uses the 2H:3H chunk)
    float p3 = pre[b][12 + d];   // g
    float it = sigf(sigf(p0));
    float ft = sigf(sigf(p1));
    float ot = sigf(sigf(p2));
    float gt = tanhf(p3);
    cstate = ft * cstate + it * gt;
    float hv = ot * tanhf(cstate);
    hlast = hv;

    // recurrence store (bf16, MALL-coherent)
    st2_coh(hbuf + ((t & 1) ^ 1) * (NB * NH) + b * NH + jcol, f2bf(hv));
    // output store: f32
    out[(((size_t)b * NT + t) << 10) + jcol] = hv;

    grid_barrier(cnt, ++bar);  // h visible device-wide; protects pre & hbuf WAR
  }

  // h_T and c_T, f32
  out[(size_t)NB * NT * NH + b * NH + jcol]           = hlast;
  out[(size_t)NB * NT * NH + NB * NH + b * NH + jcol] = cstate;
}

extern "C" void kernel_launch(void* const* d_in, const int* in_sizes, int n_in,
                              void* d_out, int out_size, void* d_ws, size_t ws_size,
                              hipStream_t stream) {
  (void)in_sizes; (void)n_in; (void)out_size;
  const float* x  = (const float*)d_in[0];
  const float* Wi = (const float*)d_in[1];
  const float* Wh = (const float*)d_in[2];
  float* out = (float*)d_out;

  // ws layout (every region gated on ws_size before use):
  //   [0,64)              barrier counter
  //   [64, 64+256KiB)     hbuf bf16 double buffer (fallback: d_out tail)
  //   [+, +64MiB)         x as bf16 (PATH A only)
  const size_t HBUF_OFF  = 64;
  const size_t XBF_OFF   = HBUF_OFF + (size_t)2 * NB * NH * 2;   // 262,208
  const size_t WS_FULL   = XBF_OFF + (size_t)NB * NT * NI * 2;   // ~67.4 MB

  unsigned* cnt = (unsigned*)d_ws;
  const bool hbuf_in_ws = ws_size >= XBF_OFF;
  const bool use_xbf    = ws_size >= WS_FULL;

  unsigned short* hbuf = hbuf_in_ws
      ? (unsigned short*)((char*)d_ws + HBUF_OFF)
      : (unsigned short*)(out + (size_t)NB * NT * NH);
  unsigned short* xbf = (unsigned short*)((char*)d_ws + XBF_OFF);

  reset_cnt<<<dim3(1), dim3(64), 0, stream>>>(cnt);

  if (use_xbf) {
    int n4 = (NB * NT * NI) / 4;
    cvt_bf16_lin<<<dim3(n4 / 256), dim3(256), 0, stream>>>(x, xbf, n4);
    lstm_seq<true><<<dim3(NWG), dim3(256), 0, stream>>>(
        nullptr, xbf, Wi, Wh, out, hbuf, cnt);
  } else {
    lstm_seq<false><<<dim3(NWG), dim3(256), 0, stream>>>(
        x, nullptr, Wi, Wh, out, hbuf, cnt);
  }
}

// Round 8
// 6689.869 us; speedup vs baseline: 4.9251x; 1.4683x over previous
//
#include <hip/hip_runtime.h>

typedef __attribute__((ext_vector_type(8))) short sv8;   // 8 x bf16 (4 VGPRs)
typedef __attribute__((ext_vector_type(4))) float fv4;   // MFMA accumulator

#define NB 64
#define NT 512
#define NI 1024
#define NH 1024
#define NWG 256

__device__ __forceinline__ unsigned short f2bf(float f) {
  union { float f; unsigned u; } v; v.f = f;
  unsigned r = v.u + 0x7fffu + ((v.u >> 16) & 1u);  // round-to-nearest-even
  return (unsigned short)(r >> 16);
}

__device__ __forceinline__ float sigf(float x) {
  return 1.0f / (1.0f + __expf(-x));
}
// tanh(x) = 2*sigmoid(2x) - 1  (saturates correctly for large |x|)
__device__ __forceinline__ float tanhfast(float x) {
  return 2.0f * sigf(2.0f * x) - 1.0f;
}

// load 8 consecutive f32 and convert to a bf16x8 MFMA fragment (in-register)
__device__ __forceinline__ sv8 ldcvt8(const float* p) {
  float4 a = *reinterpret_cast<const float4*>(p);
  float4 b = *reinterpret_cast<const float4*>(p + 4);
  union { sv8 v; unsigned short u[8]; } r;
  r.u[0] = f2bf(a.x); r.u[1] = f2bf(a.y); r.u[2] = f2bf(a.z); r.u[3] = f2bf(a.w);
  r.u[4] = f2bf(b.x); r.u[5] = f2bf(b.y); r.u[6] = f2bf(b.z); r.u[7] = f2bf(b.w);
  return r.v;
}

// MALL-coherent (agent-scope RELAXED -> sc0 sc1, no cache maintenance)
__device__ __forceinline__ unsigned long long ld8_coh(const unsigned short* p) {
  return __hip_atomic_load((const unsigned long long*)p,
                           __ATOMIC_RELAXED, __HIP_MEMORY_SCOPE_AGENT);
}
__device__ __forceinline__ void st2_coh(unsigned short* p, unsigned short v) {
  __hip_atomic_store(p, v, __ATOMIC_RELAXED, __HIP_MEMORY_SCOPE_AGENT);
}
__device__ __forceinline__ unsigned ld4_coh(const unsigned* p) {
  return __hip_atomic_load(p, __ATOMIC_RELAXED, __HIP_MEMORY_SCOPE_AGENT);
}
__device__ __forceinline__ void st4_coh(unsigned* p, unsigned v) {
  __hip_atomic_store(p, v, __ATOMIC_RELAXED, __HIP_MEMORY_SCOPE_AGENT);
}

union hfrag { sv8 v; unsigned long long q[2]; };

// zero the barrier state (counter + 256 flags spaced 64B)
__global__ void reset_bar(unsigned* cnt, unsigned* flags) {
  if (threadIdx.x == 0) st4_coh(cnt, 0u);
  if (flags) st4_coh(flags + threadIdx.x * 16, 0u);
}

// PATH A pre-pass: linear f32 -> bf16 of x into ws.
__global__ void cvt_bf16_lin(const float* __restrict__ in,
                             unsigned short* __restrict__ out, int n4) {
  int i = blockIdx.x * blockDim.x + threadIdx.x;
  if (i >= n4) return;
  float4 v = reinterpret_cast<const float4*>(in)[i];
  ushort4 o;
  o.x = f2bf(v.x); o.y = f2bf(v.y); o.z = f2bf(v.z); o.w = f2bf(v.w);
  reinterpret_cast<ushort4*>(out)[i] = o;
}

// ---- fence-free grid barrier, split into arrive / wait ----
// flags mode: WG w stores flag[w]=k (parallel, 64B-spaced); wave 0 polls all
// 256 flags with 4 independent MALL loads per lane -> no RMW serialization.
// counter mode (fallback, ws too small): round-7 behavior.
// Precondition for arrive: __syncthreads() already executed after the h-stores
// (lowers to s_waitcnt vmcnt(0) + s_barrier => sc0/sc1 stores are in MALL).
__device__ __forceinline__ void bar_arrive(unsigned* cnt, unsigned* flags,
                                           unsigned k) {
  if (flags) {
    if (threadIdx.x == 0) st4_coh(flags + blockIdx.x * 16, k);
  } else {
    if (threadIdx.x == 0)
      __hip_atomic_fetch_add(cnt, 1u, __ATOMIC_RELAXED, __HIP_MEMORY_SCOPE_AGENT);
  }
}
__device__ __forceinline__ void bar_wait(unsigned* cnt, unsigned* flags,
                                         unsigned k) {
  if (flags) {
    if (threadIdx.x < 64) {
      const unsigned* f = flags + threadIdx.x * 16;
      for (;;) {
        bool ok = (ld4_coh(f)            >= k) & (ld4_coh(f + 64 * 16)  >= k) &
                  (ld4_coh(f + 128 * 16) >= k) & (ld4_coh(f + 192 * 16) >= k);
        if (__all(ok)) break;
        __builtin_amdgcn_s_sleep(1);
      }
    }
  } else {
    if (threadIdx.x == 0) {
      const unsigned target = k * NWG;
      while (ld4_coh(cnt) < target) __builtin_amdgcn_s_sleep(4);
    }
  }
  __syncthreads();
}

// Persistent kernel, whole sequence. 256 WGs x 256 thr, 1 WG/CU.
// WG w owns h-cols 4w..4w+3 -> preact cols n = g*NH + 4w + d, tile col c=g*4+d.
// Wave wv owns batch rows 16wv..16wv+15. Weight B-fragments register-resident.
template <bool XBF>
__global__ void __launch_bounds__(256, 1) lstm_seq(
    const float* __restrict__ xf,            // [B][T][NI] f32 (d_in)
    const unsigned short* __restrict__ xb,   // [B][T][NI] bf16 (ws) or null
    const float* __restrict__ Wi,            // [4H][NI] f32
    const float* __restrict__ Wh,            // [4H][NH] f32
    float* out,                              // f32: hidden[B*T*H], h_T, c_T
    unsigned short* hbuf,                    // 2 * [NB][NH] bf16 double buffer
    unsigned* cnt, unsigned* flags)
{
  const int w    = blockIdx.x;
  const int tid  = threadIdx.x;
  const int lane = tid & 63;
  const int wv   = tid >> 6;
  const int c    = lane & 15;            // MFMA tile col
  const int ko   = (lane >> 4) << 3;     // k offset within a 32-k step
  const int n    = (c >> 2) * NH + (w << 2) + (c & 3);  // preact column

  __shared__ float pre[64][17];

  // ---- preload weight B-fragments (weight-stationary) ----
  sv8 bWi[32], bWh[32];
  {
    const float* wi = Wi + (size_t)n * NI + ko;
    const float* wh = Wh + (size_t)n * NH + ko;
#pragma unroll
    for (int kk = 0; kk < 32; ++kk) {
      union { sv8 v; unsigned short u[8]; } pi, ph;
#pragma unroll
      for (int j = 0; j < 8; ++j) {
        pi.u[j] = f2bf(wi[kk * 32 + j]);
        ph.u[j] = f2bf(wh[kk * 32 + j]);
      }
      bWi[kk] = pi.v;
      bWh[kk] = ph.v;
    }
  }

  // zero h_0 (buffer 0), coherent: 256 WGs x 256 thr == NB*NH exactly
  st2_coh(hbuf + (w << 8) + tid, 0);

  unsigned bar = 1;
  __syncthreads();
  bar_arrive(cnt, flags, bar);
  bar_wait(cnt, flags, bar);

  const int b    = tid >> 2;       // batch row in gate phase
  const int d    = tid & 3;
  const int jcol = (w << 2) + d;
  const int arow = (wv << 4) + c;  // batch row for A-fragments

  float cstate = 0.0f, hlast = 0.0f;

  for (int t = 0; t < NT; ++t) {
    const unsigned short* hr = hbuf + (t & 1) * (NB * NH) + arow * NH + ko;
    const unsigned short* xr =
        XBF ? (xb + ((size_t)arow * NT + t) * NI + ko) : nullptr;
    const float* xrf =
        XBF ? nullptr : (xf + ((size_t)arow * NT + t) * NI + ko);

    // preact(64x16) = x_t @ Wi^T + h_t @ Wh^T ; 4 independent acc chains
    fv4 a0 = {0.f, 0.f, 0.f, 0.f}, a1 = a0, a2 = a0, a3 = a0;
#pragma unroll
    for (int kk = 0; kk < 32; kk += 2) {
      sv8 ax0, ax1;
      if constexpr (XBF) {
        ax0 = *reinterpret_cast<const sv8*>(xr + kk * 32);
        ax1 = *reinterpret_cast<const sv8*>(xr + (kk + 1) * 32);
      } else {
        ax0 = ldcvt8(xrf + kk * 32);
        ax1 = ldcvt8(xrf + (kk + 1) * 32);
      }
      hfrag h0, h1;
      h0.q[0] = ld8_coh(hr + kk * 32);
      h0.q[1] = ld8_coh(hr + kk * 32 + 4);
      h1.q[0] = ld8_coh(hr + (kk + 1) * 32);
      h1.q[1] = ld8_coh(hr + (kk + 1) * 32 + 4);
      a0 = __builtin_amdgcn_mfma_f32_16x16x32_bf16(ax0,  bWi[kk],     a0, 0, 0, 0);
      a1 = __builtin_amdgcn_mfma_f32_16x16x32_bf16(h0.v, bWh[kk],     a1, 0, 0, 0);
      a2 = __builtin_amdgcn_mfma_f32_16x16x32_bf16(ax1,  bWi[kk + 1], a2, 0, 0, 0);
      a3 = __builtin_amdgcn_mfma_f32_16x16x32_bf16(h1.v, bWh[kk + 1], a3, 0, 0, 0);
    }
    fv4 acc = (a0 + a2) + (a1 + a3);

    // D layout: row = (lane>>4)*4 + r, col = lane&15 (verified m89/m91)
    {
      int prow = (wv << 4) + ((lane >> 4) << 2);
#pragma unroll
      for (int r = 0; r < 4; ++r) pre[prow + r][c] = acc[r];
    }
    __syncthreads();

    // gates: thread (b,d) reads tile cols g*4+d
    float p0 = pre[b][d];        // i
    float p1 = pre[b][4 + d];    // f
    float p2 = pre[b][8 + d];    // o (reference quirk: o uses the 2H:3H chunk)
    float p3 = pre[b][12 + d];   // g
    float it = sigf(sigf(p0));
    float ft = sigf(sigf(p1));
    float ot = sigf(sigf(p2));
    float gt = tanhfast(p3);
    cstate = ft * cstate + it * gt;
    float hv = ot * tanhfast(cstate);
    hlast = hv;

    // recurrence store (bf16, MALL-coherent), then drain, then arrive
    st2_coh(hbuf + ((t & 1) ^ 1) * (NB * NH) + b * NH + jcol, f2bf(hv));
    __syncthreads();                   // drains all waves' h stores (vmcnt 0)
    ++bar;
    bar_arrive(cnt, flags, bar);
    // f32 output store sits between arrive and wait: latency hidden
    out[(((size_t)b * NT + t) << 10) + jcol] = hv;
    bar_wait(cnt, flags, bar);         // also protects pre & hbuf WAR
  }

  // h_T and c_T, f32
  out[(size_t)NB * NT * NH + b * NH + jcol]           = hlast;
  out[(size_t)NB * NT * NH + NB * NH + b * NH + jcol] = cstate;
}

extern "C" void kernel_launch(void* const* d_in, const int* in_sizes, int n_in,
                              void* d_out, int out_size, void* d_ws, size_t ws_size,
                              hipStream_t stream) {
  (void)in_sizes; (void)n_in; (void)out_size;
  const float* x  = (const float*)d_in[0];
  const float* Wi = (const float*)d_in[1];
  const float* Wh = (const float*)d_in[2];
  float* out = (float*)d_out;

  // ws layout (every region gated on ws_size before use):
  //   [0,64)                cnt (counter-barrier fallback)
  //   [64, 64+16KiB)        256 flags, 64B-spaced (flag barrier)
  //   [16448, +256KiB)      hbuf bf16 double buffer (fallback: d_out tail)
  //   [278592, +64MiB)      x as bf16 (PATH A)
  const size_t FLAGS_OFF = 64;
  const size_t HBUF_OFF  = FLAGS_OFF + 256 * 64;                  // 16448
  const size_t XBF_OFF   = HBUF_OFF + (size_t)2 * NB * NH * 2;    // 278592
  const size_t WS_FULL   = XBF_OFF + (size_t)NB * NT * NI * 2;    // ~67.4 MB

  unsigned* cnt = (unsigned*)d_ws;
  unsigned* flags = (ws_size >= HBUF_OFF)
      ? (unsigned*)((char*)d_ws + FLAGS_OFF) : nullptr;
  const bool hbuf_in_ws = ws_size >= XBF_OFF;
  const bool use_xbf    = ws_size >= WS_FULL;

  unsigned short* hbuf = hbuf_in_ws
      ? (unsigned short*)((char*)d_ws + HBUF_OFF)
      : (unsigned short*)(out + (size_t)NB * NT * NH);
  unsigned short* xbf = (unsigned short*)((char*)d_ws + XBF_OFF);

  reset_bar<<<dim3(1), dim3(256), 0, stream>>>(cnt, flags);

  if (use_xbf) {
    int n4 = (NB * NT * NI) / 4;
    cvt_bf16_lin<<<dim3(n4 / 256), dim3(256), 0, stream>>>(x, xbf, n4);
    lstm_seq<true><<<dim3(NWG), dim3(256), 0, stream>>>(
        nullptr, xbf, Wi, Wh, out, hbuf, cnt, flags);
  } else {
    lstm_seq<false><<<dim3(NWG), dim3(256), 0, stream>>>(
        x, nullptr, Wi, Wh, out, hbuf, cnt, flags);
  }
}